// Round 3
// baseline (450.374 us; speedup 1.0000x reference)
//
#include <hip/hip_runtime.h>
#include <hip/hip_bf16.h>

#define Bc 16
#define Nn 4096
#define Cc 128
#define Ee 12288
#define Mm 64
#define NEG_SLOPE 0.2f
#define MARGIN 4.2f

// ---------------- GEMM: xw[n][b][c] = sum_k x[b][n][k] * w[k][c] ----------------
// x is [B,N,C] row-major; output stored transposed as [N,B,C] for node-gather locality.
// Fused epilogue: p[n,b] = dot(xw[n,b,:], att[:C]);  S1[n] += sum_c xw[n,b,c] (atomic).
__global__ __launch_bounds__(256) void gemm_xw(const float* __restrict__ x,
                                               const float* __restrict__ w,
                                               const float* __restrict__ att,
                                               float* __restrict__ xw,
                                               float* __restrict__ p,
                                               float* __restrict__ S1) {
    __shared__ float wlds[64 * 128];  // 32 KB: one k-half of w
    const float4* w4 = (const float4*)w;
    float4* wl4 = (float4*)wlds;

    int tx = threadIdx.x & 31;   // column quad: cols tx*4..tx*4+3
    int ty = threadIdx.x >> 5;   // 0..7 -> 8 rows each
    int rowbase = blockIdx.x * 64 + ty * 8;

    float acc[8][4];
#pragma unroll
    for (int i = 0; i < 8; i++)
#pragma unroll
        for (int j = 0; j < 4; j++) acc[i][j] = 0.f;

    const float4* xrow[8];
#pragma unroll
    for (int i = 0; i < 8; i++) xrow[i] = (const float4*)(x + (size_t)(rowbase + i) * 128);

    for (int half = 0; half < 2; ++half) {
        for (int i = threadIdx.x; i < 2048; i += 256) wl4[i] = w4[half * 2048 + i];
        __syncthreads();
#pragma unroll
        for (int k4 = 0; k4 < 16; ++k4) {
            float4 wv0 = wl4[(k4 * 4 + 0) * 32 + tx];
            float4 wv1 = wl4[(k4 * 4 + 1) * 32 + tx];
            float4 wv2 = wl4[(k4 * 4 + 2) * 32 + tx];
            float4 wv3 = wl4[(k4 * 4 + 3) * 32 + tx];
#pragma unroll
            for (int i = 0; i < 8; i++) {
                float4 xv = xrow[i][half * 16 + k4];
                acc[i][0] += xv.x * wv0.x + xv.y * wv1.x + xv.z * wv2.x + xv.w * wv3.x;
                acc[i][1] += xv.x * wv0.y + xv.y * wv1.y + xv.z * wv2.y + xv.w * wv3.y;
                acc[i][2] += xv.x * wv0.z + xv.y * wv1.z + xv.z * wv2.z + xv.w * wv3.z;
                acc[i][3] += xv.x * wv0.w + xv.y * wv1.w + xv.z * wv2.w + xv.w * wv3.w;
            }
        }
        __syncthreads();
    }

    float4 areg = ((const float4*)att)[tx];
#pragma unroll
    for (int i = 0; i < 8; i++) {
        int rr = rowbase + i;
        int b = rr >> 12;        // rr / N
        int n = rr & 4095;       // rr % N
        ((float4*)xw)[(size_t)n * 512 + b * 32 + tx] =
            make_float4(acc[i][0], acc[i][1], acc[i][2], acc[i][3]);
        float pd = acc[i][0] * areg.x + acc[i][1] * areg.y + acc[i][2] * areg.z + acc[i][3] * areg.w;
        float ss = acc[i][0] + acc[i][1] + acc[i][2] + acc[i][3];
#pragma unroll
        for (int m = 1; m < 32; m <<= 1) {
            pd += __shfl_xor(pd, m, 64);
            ss += __shfl_xor(ss, m, 64);
        }
        if (tx == 0) {
            p[n * 16 + b] = pd;
            atomicAdd(&S1[n], ss);
        }
    }
}

// ---------------- degree histograms ----------------
__global__ void hist_kernel(const int* __restrict__ nodes, const int* __restrict__ edges,
                            int* __restrict__ deg_n, int* __restrict__ deg_m) {
    int e = blockIdx.x * 256 + threadIdx.x;
    if (e < Ee) {
        atomicAdd(&deg_n[nodes[e]], 1);
        atomicAdd(&deg_m[edges[e]], 1);
    }
}

// ---------------- exclusive-scan offsets (single block) ----------------
__global__ __launch_bounds__(1024) void scan_kernel(const int* __restrict__ deg_n,
                                                    const int* __restrict__ deg_m,
                                                    int* __restrict__ off_n, int* __restrict__ off_m,
                                                    int* __restrict__ cur_n, int* __restrict__ cur_m) {
    __shared__ int s[1024];
    int t = threadIdx.x;
    int base = t * 4;
    int d0 = deg_n[base], d1 = deg_n[base + 1], d2 = deg_n[base + 2], d3 = deg_n[base + 3];
    int local = d0 + d1 + d2 + d3;
    s[t] = local;
    __syncthreads();
    for (int offs = 1; offs < 1024; offs <<= 1) {
        int v = (t >= offs) ? s[t - offs] : 0;
        __syncthreads();
        s[t] += v;
        __syncthreads();
    }
    int excl = s[t] - local;
    int o0 = excl, o1 = excl + d0, o2 = excl + d0 + d1, o3 = excl + d0 + d1 + d2;
    off_n[base] = o0; off_n[base + 1] = o1; off_n[base + 2] = o2; off_n[base + 3] = o3;
    cur_n[base] = o0; cur_n[base + 1] = o1; cur_n[base + 2] = o2; cur_n[base + 3] = o3;
    if (t == 1023) off_n[4096] = s[1023];
    if (t == 0) {
        int acc = 0;
        for (int m = 0; m < 64; m++) {
            off_m[m] = acc; cur_m[m] = acc; acc += deg_m[m];
        }
        off_m[64] = acc;
    }
}

// ---------------- fill CSR lists ----------------
__global__ void fill_kernel(const int* __restrict__ nodes, const int* __restrict__ edges,
                            int* __restrict__ cur_n, int* __restrict__ cur_m,
                            int* __restrict__ list_n, int* __restrict__ list_m) {
    int e = blockIdx.x * 256 + threadIdx.x;
    if (e < Ee) {
        int pos = atomicAdd(&cur_n[nodes[e]], 1);
        list_n[pos] = e;
        int pos2 = atomicAdd(&cur_m[edges[e]], 1);
        list_m[pos2] = e;
    }
}

// ---------------- edge_sums[m,b,c] = sum over incidences of hyperedge m of xw[node] ----
__global__ __launch_bounds__(256) void edge_sums_kernel(const float* __restrict__ xw,
                                                        const int* __restrict__ nodes,
                                                        const int* __restrict__ off_m,
                                                        const int* __restrict__ list_m,
                                                        float* __restrict__ es) {
    int m = blockIdx.x;
    int slot = blockIdx.y * 256 + threadIdx.x;  // 0..2047 across gridDim.y=8
    int beg = off_m[m], end = off_m[m + 1];
    float acc = 0.f;
    for (int i = beg; i < end; i++) {
        int e = list_m[i];
        int n = nodes[e];
        acc += xw[(size_t)n * 2048 + slot];
    }
    es[m * 2048 + slot] = acc;
}

// ---------------- per-hyperedge stats: q, sq, T ----------------
__global__ __launch_bounds__(256) void edge_stats_kernel(const float* __restrict__ es,
                                                         const float* __restrict__ att,
                                                         float* __restrict__ q,
                                                         float* __restrict__ sq,
                                                         float* __restrict__ T) {
    int m = blockIdx.x, t = threadIdx.x;
    int b = t >> 4, oc = (t & 15) * 8;
    const float* row = es + m * 2048 + b * 128 + oc;
    float qd = 0.f, sqd = 0.f, s = 0.f;
#pragma unroll
    for (int j = 0; j < 8; j++) {
        float v = row[j];
        qd += v * att[128 + oc + j];
        sqd += v * v;
        s += v;
    }
    for (int k = 1; k < 16; k <<= 1) {
        qd += __shfl_xor(qd, k, 64);
        sqd += __shfl_xor(sqd, k, 64);
        s += __shfl_xor(s, k, 64);
    }
    if ((t & 15) == 0) { q[m * 16 + b] = qd; sq[m * 16 + b] = sqd; }
    s += __shfl_xor(s, 16, 64);
    s += __shfl_xor(s, 32, 64);
    __shared__ float ws4[4];
    if ((t & 63) == 0) ws4[t >> 6] = s;
    __syncthreads();
    if (t == 0) T[m] = ws4[0] + ws4[1] + ws4[2] + ws4[3];
}

// ---------------- pairwise hyperedge loss, per-m partials ----------------
__global__ __launch_bounds__(256) void loss_kernel(const float* __restrict__ es,
                                                   const float* __restrict__ sq,
                                                   float* __restrict__ loss_part) {
    int m = blockIdx.x, t = threadIdx.x;
    __shared__ float esm[2048];
    for (int i = t; i < 2048; i += 256) esm[i] = es[m * 2048 + i];
    __syncthreads();
    int n = t >> 2, bq = t & 3;
    float part = 0.f;
#pragma unroll
    for (int u = 0; u < 4; u++) {
        int b = bq * 4 + u;
        float inner = 0.f;
        const float* er = es + n * 2048 + b * 128;
        const float* em = esm + b * 128;
        for (int c = 0; c < 128; c += 4) {
            float4 a = *(const float4*)(em + c);
            float4 o = *(const float4*)(er + c);
            inner += a.x * o.x + a.y * o.y + a.z * o.z + a.w * o.w;
        }
        float sm = sq[m * 16 + b], sn = sq[n * 16 + b];
        float cosv = inner / (sqrtf(sm) * sqrtf(sn));
        float d2 = sm + sn - 2.f * inner;
        float dist = sqrtf(fmaxf(d2, 0.f));
        part += cosv * dist + (1.f - cosv) * fmaxf(MARGIN - dist, 0.f);
    }
    part += __shfl_xor(part, 1, 64);
    part += __shfl_xor(part, 2, 64);
    float labs = fabsf(part * (1.f / 16.f));
    __shared__ float pl[64];
    if (bq == 0) pl[n] = labs;
    __syncthreads();
    if (t < 64) {
        float v = pl[t];
        for (int k = 1; k < 64; k <<= 1) v += __shfl_xor(v, k, 64);
        if (t == 0) loss_part[m] = v;
    }
}

// ---------------- alpha: leaky_relu + per-node softmax ----------------
__global__ __launch_bounds__(256) void alpha_kernel(const int* __restrict__ edges,
                                                    const int* __restrict__ off_n,
                                                    const int* __restrict__ list_n,
                                                    const float* __restrict__ p,
                                                    const float* __restrict__ q,
                                                    float* __restrict__ alpha) {
    int idx = blockIdx.x * 256 + threadIdx.x;  // 65536 = N*B
    int b = idx & 15, n = idx >> 4;
    int beg = off_n[n], end = off_n[n + 1];
    if (beg == end) return;
    float pb = p[n * 16 + b];
    float mx = -1e30f;
    for (int i = beg; i < end; i++) {
        int e = list_n[i];
        float l = pb + q[edges[e] * 16 + b];
        l = l >= 0.f ? l : NEG_SLOPE * l;
        mx = fmaxf(mx, l);
    }
    float ssum = 0.f;
    for (int i = beg; i < end; i++) {
        int e = list_n[i];
        float l = pb + q[edges[e] * 16 + b];
        l = l >= 0.f ? l : NEG_SLOPE * l;
        ssum += expf(l - mx);
    }
    float inv = 1.f / (ssum + 1e-16f);
    for (int i = beg; i < end; i++) {
        int e = list_n[i];
        float l = pb + q[edges[e] * 16 + b];
        l = l >= 0.f ? l : NEG_SLOPE * l;
        alpha[e * 16 + b] = expf(l - mx) * inv;
    }
}

// ---------------- out_e[m,b,c] = Bn[m] * sum alpha[e,b]*xw[node,b,c] ----------------
__global__ __launch_bounds__(256) void out_e_kernel(const float* __restrict__ xw,
                                                    const int* __restrict__ nodes,
                                                    const int* __restrict__ off_m,
                                                    const int* __restrict__ list_m,
                                                    const float* __restrict__ alpha,
                                                    const int* __restrict__ deg_m,
                                                    float* __restrict__ oute) {
    int m = blockIdx.x;
    int slot = blockIdx.y * 256 + threadIdx.x;
    int b = slot >> 7;
    int beg = off_m[m], end = off_m[m + 1];
    float acc = 0.f;
    for (int i = beg; i < end; i++) {
        int e = list_m[i];
        int n = nodes[e];
        acc += alpha[e * 16 + b] * xw[(size_t)n * 2048 + slot];
    }
    float d = (float)deg_m[m];
    float bn = d > 0.f ? 1.f / d : 0.f;
    oute[m * 2048 + slot] = bn * acc;
}

// ---------------- out[b,n,c] = D[n] * sum alpha[e,b]*out_e[edge,b,c] ----------------
__global__ __launch_bounds__(256) void out_kernel(const float* __restrict__ oute,
                                                  const int* __restrict__ edges,
                                                  const int* __restrict__ off_n,
                                                  const int* __restrict__ list_n,
                                                  const float* __restrict__ alpha,
                                                  float* __restrict__ out) {
    int n = blockIdx.x, t = threadIdx.x;
    int beg = off_n[n], end = off_n[n + 1];
    float d = (float)(end - beg);
    float acc[8] = {0, 0, 0, 0, 0, 0, 0, 0};
    for (int i = beg; i < end; i++) {
        int e = list_n[i];
        int m = edges[e];
        const float* er = oute + m * 2048;
#pragma unroll
        for (int k = 0; k < 8; k++) {
            int slot = t + k * 256;
            int b = slot >> 7;
            acc[k] += alpha[e * 16 + b] * er[slot];
        }
    }
#pragma unroll
    for (int k = 0; k < 8; k++) {
        int slot = t + k * 256;
        int b = slot >> 7, c = slot & 127;
        out[(size_t)b * 524288 + n * 128 + c] = d * acc[k];
    }
}

// ---------------- finalize scalar ----------------
__global__ __launch_bounds__(256) void finalize_kernel(const int* __restrict__ deg_n,
                                                       const float* __restrict__ S1,
                                                       const int* __restrict__ deg_m,
                                                       const float* __restrict__ T,
                                                       const float* __restrict__ loss_part,
                                                       float* __restrict__ out_scalar) {
    int t = threadIdx.x;
    double a = 0.0;
    for (int n = t; n < 4096; n += 256) a += (double)deg_n[n] * (double)S1[n];
    double bsum = 0.0, l = 0.0;
    if (t < 64) {
        bsum = (double)deg_m[t] * (double)T[t];
        l = (double)loss_part[t];
    }
    __shared__ double sa[256], sb[256], sl[256];
    sa[t] = a; sb[t] = bsum; sl[t] = l;
    __syncthreads();
    for (int s = 128; s > 0; s >>= 1) {
        if (t < s) { sa[t] += sa[t + s]; sb[t] += sb[t + s]; sl[t] += sl[t + s]; }
        __syncthreads();
    }
    if (t == 0) {
        double mean = (sa[0] - sb[0]) / 25165824.0;  // E*B*C
        out_scalar[0] = (float)(fabs(mean) + sl[0] / 4225.0);
    }
}

extern "C" void kernel_launch(void* const* d_in, const int* in_sizes, int n_in,
                              void* d_out, int out_size, void* d_ws, size_t ws_size,
                              hipStream_t stream) {
    const float* x = (const float*)d_in[0];
    const int* nodes = (const int*)d_in[1];
    const int* edges = (const int*)d_in[2];
    const float* w = (const float*)d_in[3];
    const float* att = (const float*)d_in[4];
    float* out = (float*)d_out;

    char* ws = (char*)d_ws;
    size_t o = 0;
    float* xw = (float*)(ws + o);        o += (size_t)Nn * Bc * Cc * 4;  // 32 MB
    float* es = (float*)(ws + o);        o += (size_t)Mm * Bc * Cc * 4;  // 512 KB
    float* oute = (float*)(ws + o);      o += (size_t)Mm * Bc * Cc * 4;  // 512 KB
    float* p = (float*)(ws + o);         o += (size_t)Nn * Bc * 4;       // 256 KB
    float* q = (float*)(ws + o);         o += (size_t)Mm * Bc * 4;
    float* sq = (float*)(ws + o);        o += (size_t)Mm * Bc * 4;
    float* alpha = (float*)(ws + o);     o += (size_t)Ee * Bc * 4;       // 768 KB
    // zero-initialized region: deg_n, deg_m, S1 (contiguous, one memset)
    int* deg_n = (int*)(ws + o);         o += (size_t)Nn * 4;
    int* deg_m = (int*)(ws + o);         o += (size_t)Mm * 4;
    float* S1 = (float*)(ws + o);        o += (size_t)Nn * 4;
    float* T = (float*)(ws + o);         o += (size_t)Mm * 4;
    float* loss_part = (float*)(ws + o); o += (size_t)Mm * 4;
    int* off_n = (int*)(ws + o);         o += (size_t)(Nn + 1) * 4;
    int* off_m = (int*)(ws + o);         o += (size_t)(Mm + 1) * 4;
    int* cur_n = (int*)(ws + o);         o += (size_t)Nn * 4;
    int* cur_m = (int*)(ws + o);         o += (size_t)Mm * 4;
    int* list_n = (int*)(ws + o);        o += (size_t)Ee * 4;
    int* list_m = (int*)(ws + o);        o += (size_t)Ee * 4;

    hipMemsetAsync(deg_n, 0, (size_t)(Nn + Mm + Nn) * sizeof(int), stream);

    gemm_xw<<<1024, 256, 0, stream>>>(x, w, att, xw, p, S1);
    hist_kernel<<<48, 256, 0, stream>>>(nodes, edges, deg_n, deg_m);
    scan_kernel<<<1, 1024, 0, stream>>>(deg_n, deg_m, off_n, off_m, cur_n, cur_m);
    fill_kernel<<<48, 256, 0, stream>>>(nodes, edges, cur_n, cur_m, list_n, list_m);
    edge_sums_kernel<<<dim3(Mm, 8), 256, 0, stream>>>(xw, nodes, off_m, list_m, es);
    edge_stats_kernel<<<Mm, 256, 0, stream>>>(es, att, q, sq, T);
    loss_kernel<<<Mm, 256, 0, stream>>>(es, sq, loss_part);
    alpha_kernel<<<256, 256, 0, stream>>>(edges, off_n, list_n, p, q, alpha);
    out_e_kernel<<<dim3(Mm, 8), 256, 0, stream>>>(xw, nodes, off_m, list_m, alpha, deg_m, oute);
    out_kernel<<<Nn, 256, 0, stream>>>(oute, edges, off_n, list_n, alpha, out);
    finalize_kernel<<<1, 256, 0, stream>>>(deg_n, S1, deg_m, T, loss_part, out + (size_t)Bc * Nn * Cc);
}

// Round 4
// 257.467 us; speedup vs baseline: 1.7493x; 1.7493x over previous
//
#include <hip/hip_runtime.h>
#include <hip/hip_bf16.h>

#define Bc 16
#define Nn 4096
#define Cc 128
#define Ee 12288
#define Mm 64
#define NEG_SLOPE 0.2f
#define MARGIN 4.2f
#define CH 4  // chunk split for segment-sum kernels

// ---------------- GEMM: xw[n][b][c] = sum_k x[b][n][k] * w[k][c] ----------------
// 128x128 tile/block, 256 threads, 8x8 outputs/thread. x staged TRANSPOSED in LDS
// (coalesced global reads, broadcast LDS reads); w half-staged (k in 64-chunks).
// Epilogue: p[n,b] = dot(xw row, att[:C]); S1[n] += row sum (atomic, zero-init).
__global__ __launch_bounds__(256) void gemm_xw(const float* __restrict__ x,
                                               const float* __restrict__ w,
                                               const float* __restrict__ att,
                                               float* __restrict__ xw,
                                               float* __restrict__ p,
                                               float* __restrict__ S1) {
    __shared__ float xT[64][132];  // [k][row], padded stride 132 (16B-aligned, banks spread)
    __shared__ float wl[64][132];  // [k][col]
    int t = threadIdx.x;
    int tc = t & 15;   // col group: cols tc*8..tc*8+7
    int tr = t >> 4;   // row group: rows tr*8..tr*8+7
    int rowbase = blockIdx.x * 128;

    float acc[8][8];
#pragma unroll
    for (int i = 0; i < 8; i++)
#pragma unroll
        for (int j = 0; j < 8; j++) acc[i][j] = 0.f;

    for (int half = 0; half < 2; ++half) {
        // stage x[rowbase..+128)[half*64..+64) transposed -> xT[k][row]
#pragma unroll
        for (int s = 0; s < 8; ++s) {
            int idx = s * 256 + t;
            int row = idx >> 4, k4 = idx & 15;
            float4 v = ((const float4*)x)[(size_t)(rowbase + row) * 32 + half * 16 + k4];
            xT[k4 * 4 + 0][row] = v.x;
            xT[k4 * 4 + 1][row] = v.y;
            xT[k4 * 4 + 2][row] = v.z;
            xT[k4 * 4 + 3][row] = v.w;
        }
        // stage w[half*64..+64)[0..128) -> wl[k][c]
#pragma unroll
        for (int s = 0; s < 8; ++s) {
            int idx = s * 256 + t;
            int k = idx >> 5, c4 = idx & 31;
            float4 v = ((const float4*)w)[(size_t)(half * 64 + k) * 32 + c4];
            *(float4*)&wl[k][c4 * 4] = v;
        }
        __syncthreads();
#pragma unroll 4
        for (int k = 0; k < 64; ++k) {
            float4 xv0 = *(const float4*)&xT[k][tr * 8];
            float4 xv1 = *(const float4*)&xT[k][tr * 8 + 4];
            float4 wv0 = *(const float4*)&wl[k][tc * 8];
            float4 wv1 = *(const float4*)&wl[k][tc * 8 + 4];
            float xs_[8] = {xv0.x, xv0.y, xv0.z, xv0.w, xv1.x, xv1.y, xv1.z, xv1.w};
            float ww_[8] = {wv0.x, wv0.y, wv0.z, wv0.w, wv1.x, wv1.y, wv1.z, wv1.w};
#pragma unroll
            for (int i = 0; i < 8; i++)
#pragma unroll
                for (int j = 0; j < 8; j++) acc[i][j] += xs_[i] * ww_[j];
        }
        __syncthreads();
    }

    float4 a0 = ((const float4*)att)[tc * 2];
    float4 a1 = ((const float4*)att)[tc * 2 + 1];
    float aw[8] = {a0.x, a0.y, a0.z, a0.w, a1.x, a1.y, a1.z, a1.w};
#pragma unroll
    for (int i = 0; i < 8; i++) {
        int rr = rowbase + tr * 8 + i;
        int b = rr >> 12;   // batch
        int n = rr & 4095;  // node
        ((float4*)xw)[(size_t)n * 512 + b * 32 + tc * 2] =
            make_float4(acc[i][0], acc[i][1], acc[i][2], acc[i][3]);
        ((float4*)xw)[(size_t)n * 512 + b * 32 + tc * 2 + 1] =
            make_float4(acc[i][4], acc[i][5], acc[i][6], acc[i][7]);
        float pd = 0.f, ss = 0.f;
#pragma unroll
        for (int j = 0; j < 8; j++) { pd += acc[i][j] * aw[j]; ss += acc[i][j]; }
        // reduce across the 16 tc lanes (masks <16 stay within the tc group)
#pragma unroll
        for (int m = 1; m < 16; m <<= 1) {
            pd += __shfl_xor(pd, m, 64);
            ss += __shfl_xor(ss, m, 64);
        }
        if (tc == 0) {
            p[n * 16 + b] = pd;
            atomicAdd(&S1[n], ss);
        }
    }
}

// ---------------- degree histograms ----------------
__global__ void hist_kernel(const int* __restrict__ nodes, const int* __restrict__ edges,
                            int* __restrict__ deg_n, int* __restrict__ deg_m) {
    int e = blockIdx.x * 256 + threadIdx.x;
    if (e < Ee) {
        atomicAdd(&deg_n[nodes[e]], 1);
        atomicAdd(&deg_m[edges[e]], 1);
    }
}

// ---------------- exclusive-scan offsets (single block) ----------------
__global__ __launch_bounds__(1024) void scan_kernel(const int* __restrict__ deg_n,
                                                    const int* __restrict__ deg_m,
                                                    int* __restrict__ off_n, int* __restrict__ off_m,
                                                    int* __restrict__ cur_n, int* __restrict__ cur_m) {
    __shared__ int s[1024];
    int t = threadIdx.x;
    int base = t * 4;
    int d0 = deg_n[base], d1 = deg_n[base + 1], d2 = deg_n[base + 2], d3 = deg_n[base + 3];
    int local = d0 + d1 + d2 + d3;
    s[t] = local;
    __syncthreads();
    for (int offs = 1; offs < 1024; offs <<= 1) {
        int v = (t >= offs) ? s[t - offs] : 0;
        __syncthreads();
        s[t] += v;
        __syncthreads();
    }
    int excl = s[t] - local;
    int o0 = excl, o1 = excl + d0, o2 = excl + d0 + d1, o3 = excl + d0 + d1 + d2;
    off_n[base] = o0; off_n[base + 1] = o1; off_n[base + 2] = o2; off_n[base + 3] = o3;
    cur_n[base] = o0; cur_n[base + 1] = o1; cur_n[base + 2] = o2; cur_n[base + 3] = o3;
    if (t == 1023) off_n[4096] = s[1023];
    if (t == 0) {
        int acc = 0;
        for (int m = 0; m < 64; m++) {
            off_m[m] = acc; cur_m[m] = acc; acc += deg_m[m];
        }
        off_m[64] = acc;
    }
}

// ---------------- fill CSR lists (+ pre-gathered ids to shorten chains) ----------------
__global__ void fill_kernel(const int* __restrict__ nodes, const int* __restrict__ edges,
                            int* __restrict__ cur_n, int* __restrict__ cur_m,
                            int* __restrict__ list_n, int* __restrict__ gedge_n,
                            int* __restrict__ list_m, int* __restrict__ gnode_m) {
    int e = blockIdx.x * 256 + threadIdx.x;
    if (e < Ee) {
        int n = nodes[e], m = edges[e];
        int pos = atomicAdd(&cur_n[n], 1);
        list_n[pos] = e;
        gedge_n[pos] = m;
        int pos2 = atomicAdd(&cur_m[m], 1);
        list_m[pos2] = e;
        gnode_m[pos2] = n;
    }
}

// ---------------- edge_sums: es[m,slot] += sum over chunk of xw[node,slot] ----------------
// grid (Mm, 8, CH); es zero-initialized; atomic cross-chunk reduce.
__global__ __launch_bounds__(256) void edge_sums_kernel(const float* __restrict__ xw,
                                                        const int* __restrict__ off_m,
                                                        const int* __restrict__ gnode_m,
                                                        float* __restrict__ es) {
    int m = blockIdx.x;
    int slot = blockIdx.y * 256 + threadIdx.x;
    int beg = off_m[m], end = off_m[m + 1];
    int len = end - beg;
    int cbeg = beg + (len * (int)blockIdx.z) / CH;
    int cend = beg + (len * ((int)blockIdx.z + 1)) / CH;
    float acc = 0.f;
    for (int i = cbeg; i < cend; i++) {
        int n = gnode_m[i];
        acc += xw[(size_t)n * 2048 + slot];
    }
    if (acc != 0.f || cend > cbeg) atomicAdd(&es[m * 2048 + slot], acc);
}

// ---------------- per-hyperedge stats: q, sq, T ----------------
__global__ __launch_bounds__(256) void edge_stats_kernel(const float* __restrict__ es,
                                                         const float* __restrict__ att,
                                                         float* __restrict__ q,
                                                         float* __restrict__ sq,
                                                         float* __restrict__ T) {
    int m = blockIdx.x, t = threadIdx.x;
    int b = t >> 4, oc = (t & 15) * 8;
    const float* row = es + m * 2048 + b * 128 + oc;
    float qd = 0.f, sqd = 0.f, s = 0.f;
#pragma unroll
    for (int j = 0; j < 8; j++) {
        float v = row[j];
        qd += v * att[128 + oc + j];
        sqd += v * v;
        s += v;
    }
    for (int k = 1; k < 16; k <<= 1) {
        qd += __shfl_xor(qd, k, 64);
        sqd += __shfl_xor(sqd, k, 64);
        s += __shfl_xor(s, k, 64);
    }
    if ((t & 15) == 0) { q[m * 16 + b] = qd; sq[m * 16 + b] = sqd; }
    s += __shfl_xor(s, 16, 64);
    s += __shfl_xor(s, 32, 64);
    __shared__ float ws4[4];
    if ((t & 63) == 0) ws4[t >> 6] = s;
    __syncthreads();
    if (t == 0) T[m] = ws4[0] + ws4[1] + ws4[2] + ws4[3];
}

// ---------------- pairwise hyperedge loss, per-m partials ----------------
__global__ __launch_bounds__(256) void loss_kernel(const float* __restrict__ es,
                                                   const float* __restrict__ sq,
                                                   float* __restrict__ loss_part) {
    int m = blockIdx.x, t = threadIdx.x;
    __shared__ float esm[2048];
    for (int i = t; i < 2048; i += 256) esm[i] = es[m * 2048 + i];
    __syncthreads();
    int n = t >> 2, bq = t & 3;
    float part = 0.f;
#pragma unroll
    for (int u = 0; u < 4; u++) {
        int b = bq * 4 + u;
        float inner = 0.f;
        const float* er = es + n * 2048 + b * 128;
        const float* em = esm + b * 128;
        for (int c = 0; c < 128; c += 4) {
            float4 a = *(const float4*)(em + c);
            float4 o = *(const float4*)(er + c);
            inner += a.x * o.x + a.y * o.y + a.z * o.z + a.w * o.w;
        }
        float sm = sq[m * 16 + b], sn = sq[n * 16 + b];
        float cosv = inner / (sqrtf(sm) * sqrtf(sn));
        float d2 = sm + sn - 2.f * inner;
        float dist = sqrtf(fmaxf(d2, 0.f));
        part += cosv * dist + (1.f - cosv) * fmaxf(MARGIN - dist, 0.f);
    }
    part += __shfl_xor(part, 1, 64);
    part += __shfl_xor(part, 2, 64);
    float labs = fabsf(part * (1.f / 16.f));
    __shared__ float pl[64];
    if (bq == 0) pl[n] = labs;
    __syncthreads();
    if (t < 64) {
        float v = pl[t];
        for (int k = 1; k < 64; k <<= 1) v += __shfl_xor(v, k, 64);
        if (t == 0) loss_part[m] = v;
    }
}

// ---------------- alpha: leaky_relu + per-node softmax (2-pass, first-elem shift) ------
__global__ __launch_bounds__(256) void alpha_kernel(const int* __restrict__ off_n,
                                                    const int* __restrict__ list_n,
                                                    const int* __restrict__ gedge_n,
                                                    const float* __restrict__ p,
                                                    const float* __restrict__ q,
                                                    float* __restrict__ alpha) {
    int idx = blockIdx.x * 256 + threadIdx.x;  // 65536 = N*B
    int b = idx & 15, n = idx >> 4;
    int beg = off_n[n], end = off_n[n + 1];
    if (beg == end) return;
    float pb = p[n * 16 + b];
    // shift by the first element's logit (softmax is shift-invariant; group spread is small)
    float lf = pb + q[gedge_n[beg] * 16 + b];
    lf = lf >= 0.f ? lf : NEG_SLOPE * lf;
    float ssum = 0.f;
    for (int i = beg; i < end; i++) {
        float l = pb + q[gedge_n[i] * 16 + b];
        l = l >= 0.f ? l : NEG_SLOPE * l;
        ssum += __expf(l - lf);
    }
    float inv = 1.f / ssum;
    for (int i = beg; i < end; i++) {
        int e = list_n[i];
        float l = pb + q[gedge_n[i] * 16 + b];
        l = l >= 0.f ? l : NEG_SLOPE * l;
        alpha[e * 16 + b] = __expf(l - lf) * inv;
    }
}

// ---------------- out_e (unscaled): oute[m,slot] += alpha[e,b]*xw[node,slot] ----------
// grid (Mm, 8, CH); oute zero-initialized; Bn scale folded into out_kernel.
__global__ __launch_bounds__(256) void out_e_kernel(const float* __restrict__ xw,
                                                    const int* __restrict__ off_m,
                                                    const int* __restrict__ list_m,
                                                    const int* __restrict__ gnode_m,
                                                    const float* __restrict__ alpha,
                                                    float* __restrict__ oute) {
    int m = blockIdx.x;
    int slot = blockIdx.y * 256 + threadIdx.x;
    int b = slot >> 7;
    int beg = off_m[m], end = off_m[m + 1];
    int len = end - beg;
    int cbeg = beg + (len * (int)blockIdx.z) / CH;
    int cend = beg + (len * ((int)blockIdx.z + 1)) / CH;
    float acc = 0.f;
    for (int i = cbeg; i < cend; i++) {
        int n = gnode_m[i];
        int e = list_m[i];
        acc += alpha[e * 16 + b] * xw[(size_t)n * 2048 + slot];
    }
    if (cend > cbeg) atomicAdd(&oute[m * 2048 + slot], acc);
}

// ---------------- out[b,n,c] = D[n] * sum alpha[e,b]*Bn[m]*oute[m,b,c] ----------------
__global__ __launch_bounds__(256) void out_kernel(const float* __restrict__ oute,
                                                  const int* __restrict__ off_n,
                                                  const int* __restrict__ list_n,
                                                  const int* __restrict__ gedge_n,
                                                  const int* __restrict__ deg_m,
                                                  const float* __restrict__ alpha,
                                                  float* __restrict__ out) {
    int n = blockIdx.x, t = threadIdx.x;
    int beg = off_n[n], end = off_n[n + 1];
    float d = (float)(end - beg);
    float acc[8] = {0, 0, 0, 0, 0, 0, 0, 0};
    for (int i = beg; i < end; i++) {
        int e = list_n[i];
        int m = gedge_n[i];
        float bn = 1.f / (float)deg_m[m];  // deg_m>0 since m has this incidence
        const float* er = oute + m * 2048;
#pragma unroll
        for (int k = 0; k < 8; k++) {
            int slot = t + k * 256;
            int b = slot >> 7;
            acc[k] += alpha[e * 16 + b] * bn * er[slot];
        }
    }
#pragma unroll
    for (int k = 0; k < 8; k++) {
        int slot = t + k * 256;
        int b = slot >> 7, c = slot & 127;
        out[(size_t)b * 524288 + n * 128 + c] = d * acc[k];
    }
}

// ---------------- finalize scalar ----------------
__global__ __launch_bounds__(256) void finalize_kernel(const int* __restrict__ deg_n,
                                                       const float* __restrict__ S1,
                                                       const int* __restrict__ deg_m,
                                                       const float* __restrict__ T,
                                                       const float* __restrict__ loss_part,
                                                       float* __restrict__ out_scalar) {
    int t = threadIdx.x;
    double a = 0.0;
    for (int n = t; n < 4096; n += 256) a += (double)deg_n[n] * (double)S1[n];
    double bsum = 0.0, l = 0.0;
    if (t < 64) {
        bsum = (double)deg_m[t] * (double)T[t];
        l = (double)loss_part[t];
    }
    __shared__ double sa[256], sb[256], sl[256];
    sa[t] = a; sb[t] = bsum; sl[t] = l;
    __syncthreads();
    for (int s = 128; s > 0; s >>= 1) {
        if (t < s) { sa[t] += sa[t + s]; sb[t] += sb[t + s]; sl[t] += sl[t + s]; }
        __syncthreads();
    }
    if (t == 0) {
        double mean = (sa[0] - sb[0]) / 25165824.0;  // E*B*C
        out_scalar[0] = (float)(fabs(mean) + sl[0] / 4225.0);
    }
}

extern "C" void kernel_launch(void* const* d_in, const int* in_sizes, int n_in,
                              void* d_out, int out_size, void* d_ws, size_t ws_size,
                              hipStream_t stream) {
    const float* x = (const float*)d_in[0];
    const int* nodes = (const int*)d_in[1];
    const int* edges = (const int*)d_in[2];
    const float* w = (const float*)d_in[3];
    const float* att = (const float*)d_in[4];
    float* out = (float*)d_out;

    char* ws = (char*)d_ws;
    size_t o = 0;
    float* xw = (float*)(ws + o);        o += (size_t)Nn * Bc * Cc * 4;  // 32 MB
    // ---- zero-init region start (one memset): es, oute, deg_n, deg_m, S1 ----
    size_t zbase = o;
    float* es = (float*)(ws + o);        o += (size_t)Mm * Bc * Cc * 4;  // 512 KB
    float* oute = (float*)(ws + o);      o += (size_t)Mm * Bc * Cc * 4;  // 512 KB
    int* deg_n = (int*)(ws + o);         o += (size_t)Nn * 4;
    int* deg_m = (int*)(ws + o);         o += (size_t)Mm * 4;
    float* S1 = (float*)(ws + o);        o += (size_t)Nn * 4;
    size_t zlen = o - zbase;
    // ---- zero-init region end ----
    float* p = (float*)(ws + o);         o += (size_t)Nn * Bc * 4;       // 256 KB
    float* q = (float*)(ws + o);         o += (size_t)Mm * Bc * 4;
    float* sq = (float*)(ws + o);        o += (size_t)Mm * Bc * 4;
    float* alpha = (float*)(ws + o);     o += (size_t)Ee * Bc * 4;       // 768 KB
    float* T = (float*)(ws + o);         o += (size_t)Mm * 4;
    float* loss_part = (float*)(ws + o); o += (size_t)Mm * 4;
    int* off_n = (int*)(ws + o);         o += (size_t)(Nn + 1) * 4;
    int* off_m = (int*)(ws + o);         o += (size_t)(Mm + 1) * 4;
    int* cur_n = (int*)(ws + o);         o += (size_t)Nn * 4;
    int* cur_m = (int*)(ws + o);         o += (size_t)Mm * 4;
    int* list_n = (int*)(ws + o);        o += (size_t)Ee * 4;
    int* gedge_n = (int*)(ws + o);       o += (size_t)Ee * 4;
    int* list_m = (int*)(ws + o);        o += (size_t)Ee * 4;
    int* gnode_m = (int*)(ws + o);       o += (size_t)Ee * 4;

    hipMemsetAsync(ws + zbase, 0, zlen, stream);

    gemm_xw<<<512, 256, 0, stream>>>(x, w, att, xw, p, S1);
    hist_kernel<<<48, 256, 0, stream>>>(nodes, edges, deg_n, deg_m);
    scan_kernel<<<1, 1024, 0, stream>>>(deg_n, deg_m, off_n, off_m, cur_n, cur_m);
    fill_kernel<<<48, 256, 0, stream>>>(nodes, edges, cur_n, cur_m,
                                        list_n, gedge_n, list_m, gnode_m);
    edge_sums_kernel<<<dim3(Mm, 8, CH), 256, 0, stream>>>(xw, off_m, gnode_m, es);
    edge_stats_kernel<<<Mm, 256, 0, stream>>>(es, att, q, sq, T);
    loss_kernel<<<Mm, 256, 0, stream>>>(es, sq, loss_part);
    alpha_kernel<<<256, 256, 0, stream>>>(off_n, list_n, gedge_n, p, q, alpha);
    out_e_kernel<<<dim3(Mm, 8, CH), 256, 0, stream>>>(xw, off_m, list_m, gnode_m, alpha, oute);
    out_kernel<<<Nn, 256, 0, stream>>>(oute, off_n, list_n, gedge_n, deg_m, alpha, out);
    finalize_kernel<<<1, 256, 0, stream>>>(deg_n, S1, deg_m, T, loss_part, out + (size_t)Bc * Nn * Cc);
}

// Round 6
// 243.391 us; speedup vs baseline: 1.8504x; 1.0578x over previous
//
#include <hip/hip_runtime.h>
#include <hip/hip_bf16.h>

#define Bc 16
#define Nn 4096
#define Cc 128
#define Ee 12288
#define Mm 64
#define NEG_SLOPE 0.2f
#define MARGIN 4.2f
#define CH 4  // chunk split for segment-sum kernels

typedef __attribute__((ext_vector_type(8))) short bfrag;   // 8 bf16 = 4 VGPR
typedef __attribute__((ext_vector_type(4))) float f32x4;   // MFMA accumulator

__device__ inline unsigned short f2bf_rne(float f) {
    unsigned u = __float_as_uint(f);
    unsigned r = u + 0x7FFFu + ((u >> 16) & 1u);
    return (unsigned short)(r >> 16);
}
__device__ inline float bfbits2f(unsigned short h) {
    return __uint_as_float(((unsigned)h) << 16);
}

// ---------------- w split+transpose+swizzle prep ----------------
// wsplit[0,32KB): whT ; [32KB,64KB): wlT. Layout: row=col c (256B of 128 bf16 k's),
// byte within row = 2k ^ ((c&7)<<4)  (XOR swizzle -> conflict-free b128 LDS reads).
__global__ __launch_bounds__(256) void wsplit_kernel(const float* __restrict__ w,
                                                     unsigned short* __restrict__ wsplit) {
    int idx = blockIdx.x * 256 + threadIdx.x;  // 16384 = 128*128
    int k = idx >> 7, c = idx & 127;
    float v = w[k * 128 + c];
    unsigned short h = f2bf_rne(v);
    float r = v - bfbits2f(h);
    unsigned short lo = f2bf_rne(r);
    int byteoff = c * 256 + ((2 * k) ^ ((c & 7) << 4));
    *(unsigned short*)((char*)wsplit + byteoff) = h;
    *(unsigned short*)((char*)wsplit + 32768 + byteoff) = lo;
}

// ---------------- GEMM via bf16 split MFMA: xw = x @ w ----------------
// 3-term split: xh*wh + xh*wl + xl*wh (xl*wl ~2^-17, dropped).
// Block = 128 rows x 128 cols, 4 waves; wave = 32 rows x 128 cols
//       = 2 row-tiles x 8 col-tiles of 16x16, K=128 as 4 steps of 32.
// Fragment maps (gfx950 16x16x32): A: lane=row(l&15), k=8*(l>>4)+j;
// B: lane=col(l&15), same k map; D: col=l&15, row=4*(l>>4)+reg  [m89-verified].
// Epilogue: store xw[n][b][c] (+p, S1 as before).
__global__ __launch_bounds__(256) void gemm_xw(const float* __restrict__ x,
                                               const unsigned short* __restrict__ wsplit,
                                               const float* __restrict__ att,
                                               float* __restrict__ xw,
                                               float* __restrict__ p,
                                               float* __restrict__ S1) {
    __shared__ unsigned short wlds[32768];  // 64KB: whT_swz | wlT_swz
    int t = threadIdx.x;
    {   // stage 64KB linearly (already swizzled in global)
        const float4* g4 = (const float4*)wsplit;
        float4* l4 = (float4*)wlds;
#pragma unroll
        for (int i = 0; i < 16; ++i) l4[i * 256 + t] = g4[i * 256 + t];
    }
    __syncthreads();

    int w = t >> 6;     // wave 0..3
    int l = t & 63;
    int lrow = l & 15;  // A-row / B-col / D-col selector
    int lk = l >> 4;    // k-chunk / D-row-group selector
    int rowbase = blockIdx.x * 128 + w * 32;

    f32x4 acc[2][8];
#pragma unroll
    for (int ti = 0; ti < 2; ++ti)
#pragma unroll
        for (int tj = 0; tj < 8; ++tj) acc[ti][tj] = (f32x4){0.f, 0.f, 0.f, 0.f};

    for (int ks = 0; ks < 4; ++ks) {
        // B fragments: 8 col-tiles, hi+lo (swizzled conflict-free b128 reads)
        bfrag bh[8], bl[8];
        int kbyte = (64 * ks + 16 * lk) ^ ((l & 7) << 4);
#pragma unroll
        for (int tj = 0; tj < 8; ++tj) {
            const char* base = (const char*)wlds + (tj * 16 + lrow) * 256 + kbyte;
            bh[tj] = *(const bfrag*)base;
            bl[tj] = *(const bfrag*)(base + 32768);
        }
        // A fragments: 2 row-tiles, convert f32 -> bf16 hi (trunc) + lo (RNE)
#pragma unroll
        for (int ti = 0; ti < 2; ++ti) {
            int row = rowbase + ti * 16 + lrow;
            const float4* xp = (const float4*)(x + (size_t)row * 128 + ks * 32 + lk * 8);
            float4 v0 = xp[0], v1 = xp[1];
            float fa[8] = {v0.x, v0.y, v0.z, v0.w, v1.x, v1.y, v1.z, v1.w};
            bfrag ah, al;
#pragma unroll
            for (int j = 0; j < 8; ++j) {
                unsigned u = __float_as_uint(fa[j]);
                unsigned hb = u & 0xFFFF0000u;
                float r = fa[j] - __uint_as_float(hb);
                unsigned ru = __float_as_uint(r);
                unsigned r2 = ru + 0x7FFFu + ((ru >> 16) & 1u);
                ah[j] = (short)(hb >> 16);
                al[j] = (short)(r2 >> 16);
            }
#pragma unroll
            for (int tj = 0; tj < 8; ++tj) {
                acc[ti][tj] = __builtin_amdgcn_mfma_f32_16x16x32_bf16(ah, bh[tj], acc[ti][tj], 0, 0, 0);
                acc[ti][tj] = __builtin_amdgcn_mfma_f32_16x16x32_bf16(ah, bl[tj], acc[ti][tj], 0, 0, 0);
                acc[ti][tj] = __builtin_amdgcn_mfma_f32_16x16x32_bf16(al, bh[tj], acc[ti][tj], 0, 0, 0);
            }
        }
    }

    // epilogue: stores + p/S1 reduction
    float aw_[8];
#pragma unroll
    for (int tj = 0; tj < 8; ++tj) aw_[tj] = att[tj * 16 + lrow];
#pragma unroll
    for (int ti = 0; ti < 2; ++ti) {
#pragma unroll
        for (int v = 0; v < 4; ++v) {
            int rr = rowbase + ti * 16 + lk * 4 + v;
            int b = rr >> 12;   // batch
            int n = rr & 4095;  // node
            float* orow = xw + (size_t)n * 2048 + b * 128;
            float pd = 0.f, ss = 0.f;
#pragma unroll
            for (int tj = 0; tj < 8; ++tj) {
                float val = acc[ti][tj][v];
                orow[tj * 16 + lrow] = val;
                pd += val * aw_[tj];
                ss += val;
            }
#pragma unroll
            for (int m = 1; m < 16; m <<= 1) {
                pd += __shfl_xor(pd, m, 64);
                ss += __shfl_xor(ss, m, 64);
            }
            if (lrow == 0) {
                p[n * 16 + b] = pd;
                atomicAdd(&S1[n], ss);
            }
        }
    }
}

// ---------------- degree histograms ----------------
__global__ void hist_kernel(const int* __restrict__ nodes, const int* __restrict__ edges,
                            int* __restrict__ deg_n, int* __restrict__ deg_m) {
    int e = blockIdx.x * 256 + threadIdx.x;
    if (e < Ee) {
        atomicAdd(&deg_n[nodes[e]], 1);
        atomicAdd(&deg_m[edges[e]], 1);
    }
}

// ---------------- exclusive-scan offsets (single block) ----------------
__global__ __launch_bounds__(1024) void scan_kernel(const int* __restrict__ deg_n,
                                                    const int* __restrict__ deg_m,
                                                    int* __restrict__ off_n, int* __restrict__ off_m,
                                                    int* __restrict__ cur_n, int* __restrict__ cur_m) {
    __shared__ int s[1024];
    int t = threadIdx.x;
    int base = t * 4;
    int d0 = deg_n[base], d1 = deg_n[base + 1], d2 = deg_n[base + 2], d3 = deg_n[base + 3];
    int local = d0 + d1 + d2 + d3;
    s[t] = local;
    __syncthreads();
    for (int offs = 1; offs < 1024; offs <<= 1) {
        int v = (t >= offs) ? s[t - offs] : 0;
        __syncthreads();
        s[t] += v;
        __syncthreads();
    }
    int excl = s[t] - local;
    int o0 = excl, o1 = excl + d0, o2 = excl + d0 + d1, o3 = excl + d0 + d1 + d2;
    off_n[base] = o0; off_n[base + 1] = o1; off_n[base + 2] = o2; off_n[base + 3] = o3;
    cur_n[base] = o0; cur_n[base + 1] = o1; cur_n[base + 2] = o2; cur_n[base + 3] = o3;
    if (t == 1023) off_n[4096] = s[1023];
    if (t == 0) {
        int acc = 0;
        for (int m = 0; m < 64; m++) {
            off_m[m] = acc; cur_m[m] = acc; acc += deg_m[m];
        }
        off_m[64] = acc;
    }
}

// ---------------- fill CSR lists (+ pre-gathered ids to shorten chains) ----------------
__global__ void fill_kernel(const int* __restrict__ nodes, const int* __restrict__ edges,
                            int* __restrict__ cur_n, int* __restrict__ cur_m,
                            int* __restrict__ list_n, int* __restrict__ gedge_n,
                            int* __restrict__ list_m, int* __restrict__ gnode_m) {
    int e = blockIdx.x * 256 + threadIdx.x;
    if (e < Ee) {
        int n = nodes[e], m = edges[e];
        int pos = atomicAdd(&cur_n[n], 1);
        list_n[pos] = e;
        gedge_n[pos] = m;
        int pos2 = atomicAdd(&cur_m[m], 1);
        list_m[pos2] = e;
        gnode_m[pos2] = n;
    }
}

// ---------------- edge_sums: es[m,slot] += sum over chunk of xw[node,slot] ----------------
__global__ __launch_bounds__(256) void edge_sums_kernel(const float* __restrict__ xw,
                                                        const int* __restrict__ off_m,
                                                        const int* __restrict__ gnode_m,
                                                        float* __restrict__ es) {
    int m = blockIdx.x;
    int slot = blockIdx.y * 256 + threadIdx.x;
    int beg = off_m[m], end = off_m[m + 1];
    int len = end - beg;
    int cbeg = beg + (len * (int)blockIdx.z) / CH;
    int cend = beg + (len * ((int)blockIdx.z + 1)) / CH;
    float acc = 0.f;
    for (int i = cbeg; i < cend; i++) {
        int n = gnode_m[i];
        acc += xw[(size_t)n * 2048 + slot];
    }
    if (acc != 0.f || cend > cbeg) atomicAdd(&es[m * 2048 + slot], acc);
}

// ---------------- per-hyperedge stats: q, sq, T ----------------
__global__ __launch_bounds__(256) void edge_stats_kernel(const float* __restrict__ es,
                                                         const float* __restrict__ att,
                                                         float* __restrict__ q,
                                                         float* __restrict__ sq,
                                                         float* __restrict__ T) {
    int m = blockIdx.x, t = threadIdx.x;
    int b = t >> 4, oc = (t & 15) * 8;
    const float* row = es + m * 2048 + b * 128 + oc;
    float qd = 0.f, sqd = 0.f, s = 0.f;
#pragma unroll
    for (int j = 0; j < 8; j++) {
        float v = row[j];
        qd += v * att[128 + oc + j];
        sqd += v * v;
        s += v;
    }
    for (int k = 1; k < 16; k <<= 1) {
        qd += __shfl_xor(qd, k, 64);
        sqd += __shfl_xor(sqd, k, 64);
        s += __shfl_xor(s, k, 64);
    }
    if ((t & 15) == 0) { q[m * 16 + b] = qd; sq[m * 16 + b] = sqd; }
    s += __shfl_xor(s, 16, 64);
    s += __shfl_xor(s, 32, 64);
    __shared__ float ws4[4];
    if ((t & 63) == 0) ws4[t >> 6] = s;
    __syncthreads();
    if (t == 0) T[m] = ws4[0] + ws4[1] + ws4[2] + ws4[3];
}

// ---------------- pairwise hyperedge loss, per-m partials ----------------
__global__ __launch_bounds__(256) void loss_kernel(const float* __restrict__ es,
                                                   const float* __restrict__ sq,
                                                   float* __restrict__ loss_part) {
    int m = blockIdx.x, t = threadIdx.x;
    __shared__ float esm[2048];
    for (int i = t; i < 2048; i += 256) esm[i] = es[m * 2048 + i];
    __syncthreads();
    int n = t >> 2, bq = t & 3;
    float part = 0.f;
#pragma unroll
    for (int u = 0; u < 4; u++) {
        int b = bq * 4 + u;
        float inner = 0.f;
        const float* er = es + n * 2048 + b * 128;
        const float* em = esm + b * 128;
        for (int c = 0; c < 128; c += 4) {
            float4 a = *(const float4*)(em + c);
            float4 o = *(const float4*)(er + c);
            inner += a.x * o.x + a.y * o.y + a.z * o.z + a.w * o.w;
        }
        float sm = sq[m * 16 + b], sn = sq[n * 16 + b];
        float cosv = inner / (sqrtf(sm) * sqrtf(sn));
        float d2 = sm + sn - 2.f * inner;
        float dist = sqrtf(fmaxf(d2, 0.f));
        part += cosv * dist + (1.f - cosv) * fmaxf(MARGIN - dist, 0.f);
    }
    part += __shfl_xor(part, 1, 64);
    part += __shfl_xor(part, 2, 64);
    float labs = fabsf(part * (1.f / 16.f));
    __shared__ float pl[64];
    if (bq == 0) pl[n] = labs;
    __syncthreads();
    if (t < 64) {
        float v = pl[t];
        for (int k = 1; k < 64; k <<= 1) v += __shfl_xor(v, k, 64);
        if (t == 0) loss_part[m] = v;
    }
}

// ---------------- alpha: leaky_relu + per-node softmax (2-pass, first-elem shift) ------
__global__ __launch_bounds__(256) void alpha_kernel(const int* __restrict__ off_n,
                                                    const int* __restrict__ list_n,
                                                    const int* __restrict__ gedge_n,
                                                    const float* __restrict__ p,
                                                    const float* __restrict__ q,
                                                    float* __restrict__ alpha) {
    int idx = blockIdx.x * 256 + threadIdx.x;  // 65536 = N*B
    int b = idx & 15, n = idx >> 4;
    int beg = off_n[n], end = off_n[n + 1];
    if (beg == end) return;
    float pb = p[n * 16 + b];
    float lf = pb + q[gedge_n[beg] * 16 + b];
    lf = lf >= 0.f ? lf : NEG_SLOPE * lf;
    float ssum = 0.f;
    for (int i = beg; i < end; i++) {
        float l = pb + q[gedge_n[i] * 16 + b];
        l = l >= 0.f ? l : NEG_SLOPE * l;
        ssum += __expf(l - lf);
    }
    float inv = 1.f / ssum;
    for (int i = beg; i < end; i++) {
        int e = list_n[i];
        float l = pb + q[gedge_n[i] * 16 + b];
        l = l >= 0.f ? l : NEG_SLOPE * l;
        alpha[e * 16 + b] = __expf(l - lf) * inv;
    }
}

// ---------------- out_e (unscaled): oute[m,slot] += alpha[e,b]*xw[node,slot] ----------
__global__ __launch_bounds__(256) void out_e_kernel(const float* __restrict__ xw,
                                                    const int* __restrict__ off_m,
                                                    const int* __restrict__ list_m,
                                                    const int* __restrict__ gnode_m,
                                                    const float* __restrict__ alpha,
                                                    float* __restrict__ oute) {
    int m = blockIdx.x;
    int slot = blockIdx.y * 256 + threadIdx.x;
    int b = slot >> 7;
    int beg = off_m[m], end = off_m[m + 1];
    int len = end - beg;
    int cbeg = beg + (len * (int)blockIdx.z) / CH;
    int cend = beg + (len * ((int)blockIdx.z + 1)) / CH;
    float acc = 0.f;
    for (int i = cbeg; i < cend; i++) {
        int n = gnode_m[i];
        int e = list_m[i];
        acc += alpha[e * 16 + b] * xw[(size_t)n * 2048 + slot];
    }
    if (cend > cbeg) atomicAdd(&oute[m * 2048 + slot], acc);
}

// ---------------- out[b,n,c] = D[n] * sum alpha[e,b]*Bn[m]*oute[m,b,c] ----------------
__global__ __launch_bounds__(256) void out_kernel(const float* __restrict__ oute,
                                                  const int* __restrict__ off_n,
                                                  const int* __restrict__ list_n,
                                                  const int* __restrict__ gedge_n,
                                                  const int* __restrict__ deg_m,
                                                  const float* __restrict__ alpha,
                                                  float* __restrict__ out) {
    int n = blockIdx.x, t = threadIdx.x;
    int beg = off_n[n], end = off_n[n + 1];
    float d = (float)(end - beg);
    float acc[8] = {0, 0, 0, 0, 0, 0, 0, 0};
    for (int i = beg; i < end; i++) {
        int e = list_n[i];
        int m = gedge_n[i];
        float bn = 1.f / (float)deg_m[m];
        const float* er = oute + m * 2048;
#pragma unroll
        for (int k = 0; k < 8; k++) {
            int slot = t + k * 256;
            int b = slot >> 7;
            acc[k] += alpha[e * 16 + b] * bn * er[slot];
        }
    }
#pragma unroll
    for (int k = 0; k < 8; k++) {
        int slot = t + k * 256;
        int b = slot >> 7, c = slot & 127;
        out[(size_t)b * 524288 + n * 128 + c] = d * acc[k];
    }
}

// ---------------- finalize scalar ----------------
__global__ __launch_bounds__(256) void finalize_kernel(const int* __restrict__ deg_n,
                                                       const float* __restrict__ S1,
                                                       const int* __restrict__ deg_m,
                                                       const float* __restrict__ T,
                                                       const float* __restrict__ loss_part,
                                                       float* __restrict__ out_scalar) {
    int t = threadIdx.x;
    double a = 0.0;
    for (int n = t; n < 4096; n += 256) a += (double)deg_n[n] * (double)S1[n];
    double bsum = 0.0, l = 0.0;
    if (t < 64) {
        bsum = (double)deg_m[t] * (double)T[t];
        l = (double)loss_part[t];
    }
    __shared__ double sa[256], sb[256], sl[256];
    sa[t] = a; sb[t] = bsum; sl[t] = l;
    __syncthreads();
    for (int s = 128; s > 0; s >>= 1) {
        if (t < s) { sa[t] += sa[t + s]; sb[t] += sb[t + s]; sl[t] += sl[t + s]; }
        __syncthreads();
    }
    if (t == 0) {
        double mean = (sa[0] - sb[0]) / 25165824.0;  // E*B*C
        out_scalar[0] = (float)(fabs(mean) + sl[0] / 4225.0);
    }
}

extern "C" void kernel_launch(void* const* d_in, const int* in_sizes, int n_in,
                              void* d_out, int out_size, void* d_ws, size_t ws_size,
                              hipStream_t stream) {
    const float* x = (const float*)d_in[0];
    const int* nodes = (const int*)d_in[1];
    const int* edges = (const int*)d_in[2];
    const float* w = (const float*)d_in[3];
    const float* att = (const float*)d_in[4];
    float* out = (float*)d_out;

    char* ws = (char*)d_ws;
    size_t o = 0;
    float* xw = (float*)(ws + o);        o += (size_t)Nn * Bc * Cc * 4;  // 32 MB
    // ---- zero-init region (one memset): es, oute, deg_n, deg_m, S1 ----
    size_t zbase = o;
    float* es = (float*)(ws + o);        o += (size_t)Mm * Bc * Cc * 4;  // 512 KB
    float* oute = (float*)(ws + o);      o += (size_t)Mm * Bc * Cc * 4;  // 512 KB
    int* deg_n = (int*)(ws + o);         o += (size_t)Nn * 4;
    int* deg_m = (int*)(ws + o);         o += (size_t)Mm * 4;
    float* S1 = (float*)(ws + o);        o += (size_t)Nn * 4;
    size_t zlen = o - zbase;
    // ---- end zero region ----
    float* p = (float*)(ws + o);         o += (size_t)Nn * Bc * 4;       // 256 KB
    float* q = (float*)(ws + o);         o += (size_t)Mm * Bc * 4;
    float* sq = (float*)(ws + o);        o += (size_t)Mm * Bc * 4;
    float* alpha = (float*)(ws + o);     o += (size_t)Ee * Bc * 4;       // 768 KB
    unsigned short* wsplit = (unsigned short*)(ws + o); o += 65536;      // 64 KB (16B-aligned)
    float* T = (float*)(ws + o);         o += (size_t)Mm * 4;
    float* loss_part = (float*)(ws + o); o += (size_t)Mm * 4;
    int* off_n = (int*)(ws + o);         o += (size_t)(Nn + 1) * 4;
    int* off_m = (int*)(ws + o);         o += (size_t)(Mm + 1) * 4;
    int* cur_n = (int*)(ws + o);         o += (size_t)Nn * 4;
    int* cur_m = (int*)(ws + o);         o += (size_t)Mm * 4;
    int* list_n = (int*)(ws + o);        o += (size_t)Ee * 4;
    int* gedge_n = (int*)(ws + o);       o += (size_t)Ee * 4;
    int* list_m = (int*)(ws + o);        o += (size_t)Ee * 4;
    int* gnode_m = (int*)(ws + o);       o += (size_t)Ee * 4;

    hipMemsetAsync(ws + zbase, 0, zlen, stream);

    wsplit_kernel<<<64, 256, 0, stream>>>(w, wsplit);
    gemm_xw<<<512, 256, 0, stream>>>(x, wsplit, att, xw, p, S1);
    hist_kernel<<<48, 256, 0, stream>>>(nodes, edges, deg_n, deg_m);
    scan_kernel<<<1, 1024, 0, stream>>>(deg_n, deg_m, off_n, off_m, cur_n, cur_m);
    fill_kernel<<<48, 256, 0, stream>>>(nodes, edges, cur_n, cur_m,
                                        list_n, gedge_n, list_m, gnode_m);
    edge_sums_kernel<<<dim3(Mm, 8, CH), 256, 0, stream>>>(xw, off_m, gnode_m, es);
    edge_stats_kernel<<<Mm, 256, 0, stream>>>(es, att, q, sq, T);
    loss_kernel<<<Mm, 256, 0, stream>>>(es, sq, loss_part);
    alpha_kernel<<<256, 256, 0, stream>>>(off_n, list_n, gedge_n, p, q, alpha);
    out_e_kernel<<<dim3(Mm, 8, CH), 256, 0, stream>>>(xw, off_m, list_m, gnode_m, alpha, oute);
    out_kernel<<<Nn, 256, 0, stream>>>(oute, off_n, list_n, gedge_n, deg_m, alpha, out);
    finalize_kernel<<<1, 256, 0, stream>>>(deg_n, S1, deg_m, T, loss_part, out + (size_t)Bc * Nn * Cc);
}